// Round 12
// baseline (111.839 us; speedup 1.0000x reference)
//
#include <hip/hip_runtime.h>
#include <math.h>

#define D   128
#define HP  32
#define WP  32
#define M   64
#define Bb  8
#define Tt  16
#define P   (HP*WP)      // 1024
#define BT  (Bb*Tt)      // 128
#define EPSF 1e-5f
#define SCALE 0.08838834764831845f   // 1/sqrt(128)

typedef __attribute__((ext_vector_type(8))) _Float16 half8;
typedef __attribute__((ext_vector_type(8))) short    short8;
typedef __attribute__((ext_vector_type(4))) float    floatx4;

// ---------------------------------------------------------------------------
// Prep: RoPE cos/sin table + Wq/Wk fp32->fp16.  (validated)
// ---------------------------------------------------------------------------
__global__ __launch_bounds__(1024)
void prep(const float* __restrict__ Wq, const float* __restrict__ Wk,
          _Float16* __restrict__ W16q, _Float16* __restrict__ W16k,
          float2* __restrict__ ropetab)
{
  const int b = blockIdx.x, t = threadIdx.x;
  if (b == 0) {
    const int gq = t >> 5, coord = t & 31;
    const float theta = __powf(100.0f, -4.0f*(float)(gq+1)/128.0f);
    float s, c;
    __sincosf(theta*(float)coord, &s, &c);
    ropetab[t] = make_float2(c, s);
  } else if (b <= 16) {
    const int i = (b-1)*1024 + t;
    W16q[i] = (_Float16)Wq[i];
  } else {
    const int i = (b-17)*1024 + t;
    W16k[i] = (_Float16)Wk[i];
  }
}

// ---------------------------------------------------------------------------
// GEMM + RoPE + LN body (validated R8/R9/R10 code, unchanged math).
// ---------------------------------------------------------------------------
template<bool IS_Q>
__device__ __forceinline__
void gemm_body(const float* __restrict__ xin,
               const _Float16* __restrict__ W16,
               const float* __restrict__ bvec,
               const float* __restrict__ g,
               const float* __restrict__ bln,
               const int*   __restrict__ positions,
               const float2* __restrict__ ropetab,
               _Float16* __restrict__ yout,
               _Float16* wl, int block0)
{
  const int tid = threadIdx.x;
  const int w = tid >> 6, lane = tid & 63;
  const int gg = lane >> 4, c = lane & 15;

  {
    const short8* wg = (const short8*)W16;
    #pragma unroll
    for (int it = 0; it < 8; ++it) {
      const int idx = tid + 256*it;
      const int row = idx >> 4, col8 = idx & 15;
      const short8 v = wg[idx];
      const int byte = row*256 + col8*16;
      *(short8*)((char*)wl + (byte ^ ((row&7)<<4))) = v;
    }
  }
  __syncthreads();

  const float* xr = xin + (size_t)(block0 + w*16 + c) * D;
  half8 aq[4];
  #pragma unroll
  for (int ks = 0; ks < 4; ++ks) {
    const float4 f0 = *(const float4*)(xr + ks*32 + gg*8);
    const float4 f1 = *(const float4*)(xr + ks*32 + gg*8 + 4);
    _Float16 h[8] = {(_Float16)f0.x,(_Float16)f0.y,(_Float16)f0.z,(_Float16)f0.w,
                     (_Float16)f1.x,(_Float16)f1.y,(_Float16)f1.z,(_Float16)f1.w};
    aq[ks] = *(half8*)h;
  }

  floatx4 acc[8];
  #pragma unroll
  for (int jt = 0; jt < 8; ++jt) {
    floatx4 a4 = (floatx4){0.f,0.f,0.f,0.f};
    #pragma unroll
    for (int ks = 0; ks < 4; ++ks) {
      const int brow = jt*16 + c;
      const int byte = brow*256 + (gg*8 + ks*32)*2;
      const half8 bf = *(const half8*)((const char*)wl + (byte ^ ((brow&7)<<4)));
      a4 = __builtin_amdgcn_mfma_f32_16x16x32_f16(aq[ks], bf, a4, 0, 0, 0);
    }
    acc[jt] = a4;
  }

  const int rr = c & 3;
  int coordv[4];
  #pragma unroll
  for (int r = 0; r < 4; ++r) {
    const int grow = block0 + w*16 + gg*4 + r;
    int hh, ww;
    if (IS_Q) { const int pos = positions[grow]; hh = pos >> 5; ww = pos & 31; }
    else      { const int p = grow & (P-1);      hh = p  >> 5; ww = p  & 31; }
    coordv[r] = (rr & 1) ? ww : hh;
  }

  float fin[8][4];
  float s1[4] = {0.f,0.f,0.f,0.f}, s2[4] = {0.f,0.f,0.f,0.f};
  #pragma unroll
  for (int jt = 0; jt < 8; ++jt) {
    const float bj = bvec[jt*16 + c];
    const int gq = jt*4 + (c >> 2);
    #pragma unroll
    for (int r = 0; r < 4; ++r) {
      const float val = acc[jt][r] + bj;
      const float2 tt = ropetab[gq*32 + coordv[r]];
      const float p2 = __shfl_xor(val, 2);
      const float f1v = (rr & 1) ? (val*tt.x + p2*tt.y)
                                 : (val*tt.x - p2*tt.y);
      const float g2 = __shfl_xor(f1v, 2);
      const float fn = (rr >= 2)
          ? ((rr & 1) ? (val*tt.x + g2*tt.y) : (val*tt.x - g2*tt.y))
          : f1v;
      fin[jt][r] = fn;
      s1[r] += fn;
      s2[r] += fn*fn;
    }
  }

  #pragma unroll
  for (int r = 0; r < 4; ++r) {
    #pragma unroll
    for (int off = 1; off <= 8; off <<= 1) {
      s1[r] += __shfl_xor(s1[r], off);
      s2[r] += __shfl_xor(s2[r], off);
    }
  }

  #pragma unroll
  for (int r = 0; r < 4; ++r) {
    const float mu   = s1[r] * (1.f/128.f);
    const float var  = s2[r] * (1.f/128.f) - mu*mu;
    const float rinv = rsqrtf(var + EPSF);
    const int grow = block0 + w*16 + gg*4 + r;
    _Float16* yo = yout + (size_t)grow * D;
    #pragma unroll
    for (int jt = 0; jt < 8; ++jt) {
      const int col = jt*16 + c;
      const float nv = (fin[jt][r] - mu) * rinv * g[col] + bln[col];
      yo[col] = (_Float16)nv;
    }
  }
}

// ---------------------------------------------------------------------------
// V^T transpose body (validated R8 transpose_v code).
// ---------------------------------------------------------------------------
__device__ __forceinline__
void transpose_body(const float* __restrict__ mv, _Float16* __restrict__ vt,
                    _Float16* xs, int block0)
{
  const int tid = threadIdx.x;
  {
    const float4* xg = (const float4*)(mv + (size_t)block0 * D);
    #pragma unroll
    for (int it = 0; it < 4; ++it) {
      const int idx = tid + 256*it;          // half8 index
      const int row = idx >> 4, col8 = idx & 15;
      const float4 f0 = xg[idx*2], f1 = xg[idx*2+1];
      _Float16 h[8] = {(_Float16)f0.x,(_Float16)f0.y,(_Float16)f0.z,(_Float16)f0.w,
                       (_Float16)f1.x,(_Float16)f1.y,(_Float16)f1.z,(_Float16)f1.w};
      const int byte = row*256 + col8*16;
      *(half8*)((char*)xs + (byte ^ ((row&7)<<4))) = *(half8*)h;
    }
  }
  __syncthreads();

  const int bt2 = block0 >> 10;
  const int p0  = block0 & (P-1);
  const int d   = tid & 127, ph = tid >> 7;
  short hv[32];
  #pragma unroll
  for (int i = 0; i < 32; ++i) {
    const int pl = ph*32 + i;
    const int byte = pl*256 + d*2;
    hv[i] = *(const short*)((const char*)xs + (byte ^ ((pl&7)<<4)));
  }
  short8* dst = (short8*)(vt + ((size_t)bt2*D + d)*P + p0 + ph*32);
  #pragma unroll
  for (int i = 0; i < 4; ++i) dst[i] = ((short8*)hv)[i];
}

// ---------------------------------------------------------------------------
// K-path: mixed-flavor grid. Even blocks: GEMM+RoPE+LN. Odd blocks: V^T.
// ---------------------------------------------------------------------------
__global__ __launch_bounds__(256)
void proj_k_mixed(const float* __restrict__ mv,
                  const _Float16* __restrict__ w16k,
                  const float* __restrict__ bk,
                  const float* __restrict__ g,
                  const float* __restrict__ bln,
                  const float2* __restrict__ ropetab,
                  _Float16* __restrict__ kout,
                  _Float16* __restrict__ vt)
{
  __shared__ _Float16 sm[128*128];   // GEMM: 32KB W ; transpose: first 16KB
  const int bx = blockIdx.x;
  const int tile = bx >> 1;
  const int block0 = tile * 64;
  if ((bx & 1) == 0)
    gemm_body<false>(mv, w16k, bk, g, bln, nullptr, ropetab, kout, sm, block0);
  else
    transpose_body(mv, vt, sm, block0);
}

// ---------------------------------------------------------------------------
// Q-path: GEMM flavor only (128 blocks).
// ---------------------------------------------------------------------------
__global__ __launch_bounds__(256)
void proj_q(const float* __restrict__ t,
            const _Float16* __restrict__ w16q,
            const float* __restrict__ bq,
            const float* __restrict__ g,
            const float* __restrict__ bln,
            const int*   __restrict__ positions,
            const float2* __restrict__ ropetab,
            _Float16* __restrict__ qout)
{
  __shared__ _Float16 sm[128*128];
  gemm_body<true>(t, w16q, bq, g, bln, positions, ropetab, qout, sm,
                  blockIdx.x * 64);
}

// ---------------------------------------------------------------------------
// Flash attention, fixed-max softmax (m=4), patch-halved grid (1024 blocks).
// RACE FIX (R12): pl and o16 are now SEPARATE LDS buffers, and a barrier
// orders loop completion (all waves' pl reads) before the epilogue writes.
// R9-R11 aliased them with different per-wave strides and no barrier -- wave
// 0's o16 writes could corrupt wave 1's in-flight P tile.
// Bound proof as R9: P = exp(s-4) in [2.2e-7, 1500], fp16-safe.
// ---------------------------------------------------------------------------
__global__ __launch_bounds__(256)
void attn_mfma(const _Float16* __restrict__ q,
               const _Float16* __restrict__ k,
               const _Float16* __restrict__ vt,   // (BT, D, P)
               const int* __restrict__ positions,
               float* __restrict__ opart,         // [2][BT*M][D]
               float* __restrict__ lpart)         // [2][BT*M]
{
  const int bt   = blockIdx.x & (BT-1);   // same-bt blocks -> same XCD
  const int rest = blockIdx.x >> 7;
  const int qq   = rest & 3;
  const int hf   = rest >> 2;             // 0/1: patch half
  const int tid = threadIdx.x;
  const int w   = tid >> 6, lane = tid & 63;
  const int g   = lane >> 4, c = lane & 15;

  __shared__ _Float16 pl[4][16][88];      // 11 KB  (loop)
  __shared__ _Float16 o16[4][16][136];    // 17.4 KB (epilogue)
  __shared__ float    l_lds[4][16];

  const _Float16* qrow = q + (size_t)(bt*M + qq*16 + c) * D + g*8;
  half8 aq[4];
  #pragma unroll
  for (int ks = 0; ks < 4; ++ks) aq[ks] = *(const half8*)(qrow + ks*32);

  float ph[4], pw[4];
  #pragma unroll
  for (int r = 0; r < 4; ++r) {
    const int pos = positions[bt*M + qq*16 + g*4 + r];
    ph[r] = (float)(pos >> 5); pw[r] = (float)(pos & 31);
  }

  float lsum[4] = {0.f, 0.f, 0.f, 0.f};
  floatx4 oacc[8];
  #pragma unroll
  for (int dt = 0; dt < 8; ++dt) oacc[dt] = (floatx4){0.f,0.f,0.f,0.f};

  const _Float16* kb = k  + ((size_t)bt * P) * D;
  const _Float16* vb = vt + ((size_t)bt * D) * P;

  for (int t = 0; t < 2; ++t) {
    const int p0 = hf*512 + w*128 + t*64;

    floatx4 s[4];
    #pragma unroll
    for (int pt = 0; pt < 4; ++pt) {
      floatx4 a4 = (floatx4){0.f,0.f,0.f,0.f};
      const _Float16* krow = kb + (size_t)(p0 + pt*16 + c) * D + g*8;
      #pragma unroll
      for (int ks = 0; ks < 4; ++ks)
        a4 = __builtin_amdgcn_mfma_f32_16x16x32_f16(
                 aq[ks], *(const half8*)(krow + ks*32), a4, 0, 0, 0);
      s[pt] = a4;
    }

    #pragma unroll
    for (int pt = 0; pt < 4; ++pt) {
      const int pp = p0 + pt*16 + c;
      const float hh = (float)(pp >> 5), ww = (float)(pp & 31);
      #pragma unroll
      for (int r = 0; r < 4; ++r) {
        const float dx = ph[r] - hh, dy = pw[r] - ww;
        const float sv = s[pt][r]*SCALE - 0.125f*sqrtf(dx*dx + dy*dy);
        const float e  = __expf(sv - 4.0f);
        const _Float16 eh = (_Float16)e;
        pl[w][g*4 + r][pt*16 + c] = eh;
        lsum[r] += (float)eh;
      }
    }

    #pragma unroll
    for (int ks = 0; ks < 2; ++ks) {
      const half8 pa = *(const half8*)(&pl[w][c][ks*32 + g*8]);
      #pragma unroll
      for (int dt = 0; dt < 8; ++dt) {
        const half8 bv = *(const half8*)(vb + (size_t)(dt*16 + c)*P
                                            + p0 + ks*32 + g*8);
        oacc[dt] = __builtin_amdgcn_mfma_f32_16x16x32_f16(pa, bv, oacc[dt], 0,0,0);
      }
    }
  }

  __syncthreads();   // RACE FIX: all waves done with pl before epilogue writes

  #pragma unroll
  for (int r = 0; r < 4; ++r) {
    #pragma unroll
    for (int off = 1; off <= 8; off <<= 1)
      lsum[r] += __shfl_xor(lsum[r], off);
  }
  if (c == 0) {
    #pragma unroll
    for (int r = 0; r < 4; ++r) l_lds[w][g*4 + r] = lsum[r];
  }

  #pragma unroll
  for (int dt = 0; dt < 8; ++dt)
    #pragma unroll
    for (int r = 0; r < 4; ++r)
      o16[w][g*4 + r][dt*16 + c] = (_Float16)oacc[dt][r];
  __syncthreads();

  // partial merge of this block's 4 waves -> fp32 partial O + L
  const int qi = tid >> 4, dg = tid & 15;
  const int row = bt*M + qq*16 + qi;
  const float L = l_lds[0][qi] + l_lds[1][qi] + l_lds[2][qi] + l_lds[3][qi];
  float a2[8] = {0.f,0.f,0.f,0.f,0.f,0.f,0.f,0.f};
  #pragma unroll
  for (int w2 = 0; w2 < 4; ++w2) {
    const half8 ov = *(const half8*)(&o16[w2][qi][dg*8]);
    #pragma unroll
    for (int dd = 0; dd < 8; ++dd) a2[dd] += (float)ov[dd];
  }
  float* orow = opart + (size_t)hf*(BT*M*D) + (size_t)row*D + dg*8;
  #pragma unroll
  for (int dd = 0; dd < 8; ++dd) orow[dd] = a2[dd];
  if (dg == 0) lpart[hf*(BT*M) + row] = L;
}

// ---------------------------------------------------------------------------
// Final merge: out = (Oa + Ob) / (La + Lb).  8 rows per block.
// ---------------------------------------------------------------------------
__global__ __launch_bounds__(256)
void attn_merge(const float* __restrict__ opart,
                const float* __restrict__ lpart,
                float* __restrict__ out)
{
  const int row = blockIdx.x*8 + (threadIdx.x >> 5);
  const int c4  = (threadIdx.x & 31) * 4;
  const float L = lpart[row] + lpart[BT*M + row];
  const float inv = 1.0f / L;
  const float4 a = *(const float4*)(opart + (size_t)row*D + c4);
  const float4 b = *(const float4*)(opart + (size_t)(BT*M)*D + (size_t)row*D + c4);
  float4 o;
  o.x = (a.x + b.x)*inv; o.y = (a.y + b.y)*inv;
  o.z = (a.z + b.z)*inv; o.w = (a.w + b.w)*inv;
  *(float4*)(out + (size_t)row*D + c4) = o;
}

// ---------------------------------------------------------------------------
extern "C" void kernel_launch(void* const* d_in, const int* in_sizes, int n_in,
                              void* d_out, int out_size, void* d_ws, size_t ws_size,
                              hipStream_t stream) {
  const float* t    = (const float*)d_in[0];
  const float* mv   = (const float*)d_in[1];
  const int*   pos  = (const int*)  d_in[2];
  const float* Wq   = (const float*)d_in[3];
  const float* bq   = (const float*)d_in[4];
  const float* Wk   = (const float*)d_in[5];
  const float* bk   = (const float*)d_in[6];
  const float* ln_g = (const float*)d_in[7];
  const float* ln_b = (const float*)d_in[8];
  float* out = (float*)d_out;

  _Float16* qbuf = (_Float16*)d_ws;                 // 1,048,576 halfs
  _Float16* kbuf = qbuf + (size_t)BT*M*D;           // 16,777,216
  _Float16* vtbf = kbuf + (size_t)BT*P*D;           // 16,777,216
  _Float16* w16q = vtbf + (size_t)BT*P*D;           // 16,384
  _Float16* w16k = w16q + D*D;                      // 16,384
  float2*   rtab = (float2*)(w16k + D*D);           // 1,024 float2
  float*    opart = (float*)(rtab + 1024);          // 2 * 1,048,576 floats
  float*    lpart = opart + 2*(size_t)BT*M*D;       // 2 * 8,192 floats

  prep<<<33, 1024, 0, stream>>>(Wq, Wk, w16q, w16k, rtab);
  proj_k_mixed<<<2*BT*P/64, 256, 0, stream>>>(mv, w16k, bk, ln_g, ln_b,
                                              rtab, kbuf, vtbf);
  proj_q<<<BT*M/64, 256, 0, stream>>>(t, w16q, bq, ln_g, ln_b, pos, rtab, qbuf);
  attn_mfma<<<1024, 256, 0, stream>>>(qbuf, kbuf, vtbf, pos, opart, lpart);
  attn_merge<<<BT*M/8, 256, 0, stream>>>(opart, lpart, out);
}